// Round 1
// baseline (620.701 us; speedup 1.0000x reference)
//
#include <hip/hip_runtime.h>

typedef __attribute__((ext_vector_type(4))) float floatx4;

#define NH 512          // HIDDEN (number of 16x16 weight matrices)
#define NB 512          // batch
#define TILE 256        // 16x16 tile elems
#define BPW 32          // b-iterations per wave

// Inputs/outputs are FP32 (reference dtype). Memory-bound: 268 MB total
// traffic -> ~43 us roofline. VALU fp32 compute floor ~14 us, so pure-VALU
// exact fp32 math; no MFMA (no fp32-input MFMA on CDNA4, bf16 cast risks
// the 7.1e-2 absmax threshold).
//
// One wave per (h, 32-b chunk). Lane = (o = lane>>2, gq = lane&3):
// owns y[o][4gq..4gq+3] (float4). W row o (16 fp32) lives in VGPRs for the
// whole b-loop. Each x-load instruction fetches exactly one 64B tile row
// (lanes with equal gq share addresses -> merged); the store writes a dense
// 1KB tile. HBM traffic is exactly minimal.
__global__ __launch_bounds__(256, 4) void GlobalMixer_kernel(
    const float* __restrict__ x,
    const float* __restrict__ w,
    float* __restrict__ y)
{
    const int lane = threadIdx.x & 63;
    const int wv   = threadIdx.x >> 6;
    const int gid  = blockIdx.x * 4 + wv;   // 0..8191
    const int h    = gid & (NH - 1);        // 512 h values
    const int b0   = (gid >> 9) * BPW;      // 16 chunks * 32 b = 512
    const int o    = lane >> 2;             // output row 0..15
    const int g0   = (lane & 3) * 4;        // output col group 0,4,8,12

    // ---- W row o of matrix h: 16 fp32, kept in registers across the b-loop
    const float* wrow_p = w + h * TILE + o * 16;
    float wr[16];
    #pragma unroll
    for (int i = 0; i < 4; ++i) {
        floatx4 wq = *(const floatx4*)(wrow_p + i * 4);
        wr[i * 4 + 0] = wq.x; wr[i * 4 + 1] = wq.y;
        wr[i * 4 + 2] = wq.z; wr[i * 4 + 3] = wq.w;
    }

    const size_t bstride = (size_t)NH * TILE;            // elems between b's
    const size_t tile0   = ((size_t)b0 * NH + h) * TILE;
    const float* xp = x + tile0 + g0;
    float*       yp = y + tile0 + o * 16 + g0;

    for (int bi = 0; bi < BPW; ++bi) {
        floatx4 acc = {0.f, 0.f, 0.f, 0.f};
        #pragma unroll
        for (int i = 0; i < 16; ++i) {
            floatx4 xv = *(const floatx4*)(xp + i * 16);  // one 64B row/wave
            acc += wr[i] * xv;
        }
        *(floatx4*)yp = acc;

        xp += bstride;
        yp += bstride;
    }
}

extern "C" void kernel_launch(void* const* d_in, const int* in_sizes, int n_in,
                              void* d_out, int out_size, void* d_ws, size_t ws_size,
                              hipStream_t stream) {
    const float* x = (const float*)d_in[0];   // (512, 512, 1, 256) fp32
    const float* w = (const float*)d_in[1];   // (512, 16, 16) fp32
    float*       y = (float*)d_out;           // (512, 512, 1, 256) fp32

    dim3 grid(2048), block(256);
    hipLaunchKernelGGL(GlobalMixer_kernel, grid, block, 0, stream, x, w, y);
}